// Round 8
// baseline (268.225 us; speedup 1.0000x reference)
//
#include <hip/hip_runtime.h>
#include <hip/hip_bf16.h>

#define HID      64
#define N_CLS    8
#define N_GRAPHS 500
#define PAD      64      // padded CSR stride; in-degree ~Poisson(16), P(>=64) ~ 1e-17
#define BW       128     // nodes per bucket
#define NB       391     // ceil(50000/128)
#define CAP      4096    // edge capacity per bucket (mean 2046)
#define CHUNK    4096    // edges per pass-1 block

// ---------------- pass 1: bin edges by col bucket (LDS-staged) + batch hist ----------------
__global__ __launch_bounds__(256) void k_bin(const int* __restrict__ row,
                                             const int* __restrict__ col, int E,
                                             int* __restrict__ gcur,
                                             unsigned int* __restrict__ ebuf,
                                             const int* __restrict__ batch, int N,
                                             int* __restrict__ bcnt) {
    int nE = (E + CHUNK - 1) / CHUNK;
    if ((int)blockIdx.x >= nE) {
        int i = (blockIdx.x - nE) * 256 + threadIdx.x;
        if (i < N) atomicAdd(&bcnt[batch[i]], 1);
        return;
    }
    __shared__ int hist[NB];
    __shared__ int base[NB];
    int t = threadIdx.x;
    for (int i = t; i < NB; i += 256) hist[i] = 0;
    __syncthreads();
    int e0 = blockIdx.x * CHUNK;
    int eend = min(e0 + CHUNK, E);
    for (int e = e0 + t; e < eend; e += 256) {
        int b = col[e] >> 7;
        atomicAdd(&hist[b], 1);                    // LDS atomic
    }
    __syncthreads();
    for (int i = t; i < NB; i += 256) {
        base[i] = atomicAdd(&gcur[i], hist[i]);    // one global atomic per (block,bucket)
        hist[i] = 0;                               // reuse as local cursor
    }
    __syncthreads();
    for (int e = e0 + t; e < eend; e += 256) {
        int c = col[e];
        int b = c >> 7;
        int slot = atomicAdd(&hist[b], 1) + base[b];   // LDS atomic
        if (slot < CAP)
            ebuf[(size_t)b * CAP + slot] = ((unsigned)(c & (BW - 1)) << 16) | (unsigned)row[e];
    }
}

// ---------------- pass 2: fill padded CSR per bucket (L2-local, no global atomics) ----------------
__global__ __launch_bounds__(256) void k_fill(const int* __restrict__ gcur,
                                              const unsigned int* __restrict__ ebuf,
                                              unsigned short* __restrict__ adj,
                                              int* __restrict__ cnt, int N) {
    int b = blockIdx.x;
    __shared__ int lcnt[BW];
    int t = threadIdx.x;
    if (t < BW) lcnt[t] = 0;
    __syncthreads();
    int m = min(gcur[b], CAP);
    const unsigned int* eb = ebuf + (size_t)b * CAP;
    for (int i = t; i < m; i += 256) {
        unsigned u = eb[i];
        int cl = u >> 16;
        int r  = u & 0xFFFF;
        int p = atomicAdd(&lcnt[cl], 1);           // LDS atomic
        if (p < PAD) adj[((size_t)(b * BW + cl)) * PAD + p] = (unsigned short)r;
    }
    __syncthreads();
    int node = b * BW + t;
    if (t < BW && node < N) cnt[node] = lcnt[t];
}

// ---------------- GEMM [N,64]@[64,64], epilogue * rsqrt(deg) ----------------
__global__ __launch_bounds__(256) void k_gemm64(const float* __restrict__ H,
                                                const float* __restrict__ W,
                                                const int* __restrict__ cnt,
                                                float* __restrict__ O, int N) {
    __shared__ float Ws[64 * 64];
    int tid = threadIdx.x;
    #pragma unroll
    for (int i = tid; i < 64 * 64; i += 256) Ws[i] = W[i];
    __syncthreads();
    int c = tid & 63;
    float w[64];
    #pragma unroll
    for (int k = 0; k < 64; ++k) w[k] = Ws[k * 64 + c];

    int rbase = blockIdx.x * 32 + (tid >> 6) * 8;
    #pragma unroll 1
    for (int it = 0; it < 8; it += 2) {
        int r0 = rbase + it;
        if (r0 >= N) break;                         // wave-uniform
        int r0u = __builtin_amdgcn_readfirstlane(r0);
        int has1 = (r0u + 1 < N);
        const float* __restrict__ h0 = H + (size_t)r0u * HID;
        const float* __restrict__ h1 = H + (size_t)(has1 ? r0u + 1 : r0u) * HID;
        float a0 = 0.f, a1 = 0.f, a2 = 0.f, a3 = 0.f;
        float b0 = 0.f, b1 = 0.f, b2 = 0.f, b3 = 0.f;
        #pragma unroll
        for (int k = 0; k < 64; k += 4) {
            a0 = fmaf(h0[k],     w[k],     a0);
            b0 = fmaf(h1[k],     w[k],     b0);
            a1 = fmaf(h0[k + 1], w[k + 1], a1);
            b1 = fmaf(h1[k + 1], w[k + 1], b1);
            a2 = fmaf(h0[k + 2], w[k + 2], a2);
            b2 = fmaf(h1[k + 2], w[k + 2], b2);
            a3 = fmaf(h0[k + 3], w[k + 3], a3);
            b3 = fmaf(h1[k + 3], w[k + 3], b3);
        }
        float d0 = rsqrtf((float)cnt[r0u] + 1.0f);
        O[(size_t)r0u * HID + c] = ((a0 + a1) + (a2 + a3)) * d0;
        if (has1) {
            float d1 = rsqrtf((float)cnt[r0u + 1] + 1.0f);
            O[(size_t)(r0u + 1) * HID + c] = ((b0 + b1) + (b2 + b3)) * d1;
        }
    }
}

// ---------------- gather-aggregate: one wave per node, quad layout ----------------
__global__ __launch_bounds__(256) void k_gather(const unsigned short* __restrict__ adj,
                                                const int* __restrict__ cnt,
                                                const float* __restrict__ xws,
                                                const float* __restrict__ b,
                                                float* __restrict__ out,
                                                int N, int do_relu) {
    int node = blockIdx.x * 4 + (threadIdx.x >> 6);
    if (node >= N) return;                      // wave-uniform
    int lane = threadIdx.x & 63;
    int q = lane >> 4, j = lane & 15;
    size_t s = (size_t)node * PAD;
    int n = cnt[node];

    float ax = 0.f, ay = 0.f, az = 0.f, aw = 0.f;
    for (int i = q; i < n; i += 4) {
        int r = adj[s + i];
        const float4 v = *reinterpret_cast<const float4*>(xws + (size_t)r * HID + j * 4);
        ax += v.x; ay += v.y; az += v.z; aw += v.w;
    }
    if (q == 0) {   // self loop
        const float4 sv = *reinterpret_cast<const float4*>(xws + (size_t)node * HID + j * 4);
        ax += sv.x; ay += sv.y; az += sv.z; aw += sv.w;
    }
    ax += __shfl_xor(ax, 16, 64); ay += __shfl_xor(ay, 16, 64);
    az += __shfl_xor(az, 16, 64); aw += __shfl_xor(aw, 16, 64);
    ax += __shfl_xor(ax, 32, 64); ay += __shfl_xor(ay, 32, 64);
    az += __shfl_xor(az, 32, 64); aw += __shfl_xor(aw, 32, 64);

    if (q == 0) {
        float d = rsqrtf((float)n + 1.0f);
        const float4 bv = *reinterpret_cast<const float4*>(b + j * 4);
        float4 o;
        o.x = ax * d + bv.x; o.y = ay * d + bv.y;
        o.z = az * d + bv.z; o.w = aw * d + bv.w;
        if (do_relu) {
            o.x = fmaxf(o.x, 0.f); o.y = fmaxf(o.y, 0.f);
            o.z = fmaxf(o.z, 0.f); o.w = fmaxf(o.w, 0.f);
        }
        *reinterpret_cast<float4*>(out + (size_t)node * HID + j * 4) = o;
    }
}

// ---------------- fused bstart-scan + mean pool + head: one block per graph ----------------
__global__ __launch_bounds__(256) void k_pmean(const float* __restrict__ h,
                                               const int* __restrict__ bcnt,
                                               const float* __restrict__ Wl,
                                               const float* __restrict__ bl,
                                               float* __restrict__ out) {
    int g = blockIdx.x;
    int t = threadIdx.x;
    __shared__ int ssum[256];
    int part = 0;
    for (int j = t; j < g; j += 256) part += bcnt[j];
    ssum[t] = part;
    __syncthreads();
    for (int s2 = 128; s2 > 0; s2 >>= 1) {
        if (t < s2) ssum[t] += ssum[t + s2];
        __syncthreads();
    }
    int s = ssum[0];
    int n = bcnt[g];
    int f = t & 63, w = t >> 6;
    float acc = 0.0f;
    for (int i = s + w; i < s + n; i += 4) acc += h[(size_t)i * HID + f];
    __shared__ float lds[256];
    __shared__ float mean[64];
    lds[t] = acc;
    __syncthreads();
    if (w == 0) {
        float tot = lds[f] + lds[64 + f] + lds[128 + f] + lds[192 + f];
        mean[f] = tot / fmaxf((float)n, 1.0f);
    }
    __syncthreads();
    if (t < N_CLS) {
        int c = t;
        float a = bl[c];
        #pragma unroll
        for (int k = 0; k < HID; ++k) a = fmaf(mean[k], Wl[k * N_CLS + c], a);
        out[(size_t)g * N_CLS + c] = a;
    }
}

extern "C" void kernel_launch(void* const* d_in, const int* in_sizes, int n_in,
                              void* d_out, int out_size, void* d_ws, size_t ws_size,
                              hipStream_t stream) {
    const float* x     = (const float*)d_in[0];
    const int*   ei    = (const int*)d_in[1];
    const int*   batch = (const int*)d_in[2];
    const float* W1    = (const float*)d_in[3];
    const float* b1    = (const float*)d_in[4];
    const float* W2    = (const float*)d_in[5];
    const float* b2    = (const float*)d_in[6];
    const float* W3    = (const float*)d_in[7];
    const float* b3    = (const float*)d_in[8];
    const float* Wl    = (const float*)d_in[9];
    const float* bl    = (const float*)d_in[10];
    float* out = (float*)d_out;

    const int N = in_sizes[0] / HID;   // 50000
    const int E = in_sizes[1] / 2;     // 800000
    const int* row = ei;
    const int* col = ei + E;

    // ---- workspace layout (4-byte units); gcur|bcnt contiguous for one memset ----
    char* wsb = (char*)d_ws;
    int*   gcur = (int*)wsb;                               // NB (392 padded)
    int*   bcnt = gcur + 392;                              // 512
    int*   cnt  = bcnt + 512;                              // 50048
    unsigned int* ebuf = (unsigned int*)(cnt + 50048);     // NB*CAP = 6.4 MB
    unsigned short* adj = (unsigned short*)(ebuf + (size_t)NB * CAP);  // 50048*64 u16
    float* bufA = (float*)(adj + (size_t)50048 * PAD);     // N*64
    float* bufB = bufA + (size_t)N * HID;                  // N*64

    const int T = 256;
    const int nblk  = (N + 255) / 256;                  // 196
    const int nEb   = (E + CHUNK - 1) / CHUNK;          // 196
    const int gGemm = (N + 31) / 32;                    // 1563
    const int gGath = (N + 3) / 4;                      // 12500

    // zero: gcur + bcnt only
    hipMemsetAsync(gcur, 0, (size_t)(392 + 512) * sizeof(int), stream);

    // ---- two-level CSR build + batch histogram ----
    k_bin <<<nEb + nblk, T, 0, stream>>>(row, col, E, gcur, ebuf, batch, N, bcnt);
    k_fill<<<NB, T, 0, stream>>>(gcur, ebuf, adj, cnt, N);

    // ---- layer 1 ----
    k_gemm64<<<gGemm, T, 0, stream>>>(x, W1, cnt, bufA, N);
    k_gather<<<gGath, T, 0, stream>>>(adj, cnt, bufA, b1, bufB, N, 1);
    // ---- layer 2 ----
    k_gemm64<<<gGemm, T, 0, stream>>>(bufB, W2, cnt, bufA, N);
    k_gather<<<gGath, T, 0, stream>>>(adj, cnt, bufA, b2, bufB, N, 1);
    // ---- layer 3 ----
    k_gemm64<<<gGemm, T, 0, stream>>>(bufB, W3, cnt, bufA, N);
    k_gather<<<gGath, T, 0, stream>>>(adj, cnt, bufA, b3, bufB, N, 0);

    // ---- fused scan + pool + head ----
    k_pmean<<<N_GRAPHS, T, 0, stream>>>(bufB, bcnt, Wl, bl, out);
}

// Round 9
// 253.591 us; speedup vs baseline: 1.0577x; 1.0577x over previous
//
#include <hip/hip_runtime.h>
#include <hip/hip_bf16.h>

#define HID      64
#define N_CLS    8
#define N_GRAPHS 500
#define PAD      64      // padded CSR stride; in-degree ~Poisson(16), P(>=64) ~ 1e-17
#define BW       128     // nodes per bucket
#define NB       391     // ceil(50000/128)
#define CAP      4096    // edge capacity per bucket (Poisson(2048), CAP = mean + 45 sigma)
#define CHUNK    2048    // edges per bin block

// ============ fused: edge-binning + batch-hist + pure layer-1 GEMM ============
// bin blocks are latency-bound (LDS atomics, dependent loads); gemm blocks are
// VALU-bound -> co-scheduling them on the same CUs hides bin latency.
__global__ __launch_bounds__(256) void k_bin_gemm(
        const int* __restrict__ row, const int* __restrict__ col, int E,
        int* __restrict__ gcur, unsigned int* __restrict__ ebuf,
        const int* __restrict__ batch, int N, int* __restrict__ bcnt,
        const float* __restrict__ Hx, const float* __restrict__ W1,
        float* __restrict__ O) {
    __shared__ char smem[16384];
    int nEb = (E + CHUNK - 1) / CHUNK;
    int nH  = (N + 255) / 256;
    int t = threadIdx.x;

    if ((int)blockIdx.x < nEb) {
        // ---- bin edges by col bucket ----
        int* hist = (int*)smem;          // NB
        int* base = hist + NB;           // NB
        for (int i = t; i < NB; i += 256) hist[i] = 0;
        __syncthreads();
        int e0 = blockIdx.x * CHUNK;
        int eend = min(e0 + CHUNK, E);
        for (int e = e0 + t; e < eend; e += 256) {
            int b = col[e] >> 7;
            atomicAdd(&hist[b], 1);                    // LDS atomic
        }
        __syncthreads();
        for (int i = t; i < NB; i += 256) {
            base[i] = atomicAdd(&gcur[i], hist[i]);    // one global atomic per (block,bucket)
            hist[i] = 0;                               // reuse as local cursor
        }
        __syncthreads();
        for (int e = e0 + t; e < eend; e += 256) {
            int c = col[e];
            int b = c >> 7;
            int slot = atomicAdd(&hist[b], 1) + base[b];
            if (slot < CAP)
                ebuf[(size_t)b * CAP + slot] =
                    ((unsigned)(c & (BW - 1)) << 16) | (unsigned)row[e];
        }
        return;
    }
    if ((int)blockIdx.x < nEb + nH) {
        // ---- batch histogram ----
        int i = (blockIdx.x - nEb) * 256 + t;
        if (i < N) atomicAdd(&bcnt[batch[i]], 1);
        return;
    }
    // ---- pure GEMM: O = Hx @ W1 (no dinv; applied in gather edge_scale mode) ----
    int gb = blockIdx.x - nEb - nH;
    float* Ws = (float*)smem;
    #pragma unroll
    for (int i = t; i < 64 * 64; i += 256) Ws[i] = W1[i];
    __syncthreads();
    int c = t & 63;
    float w[64];
    #pragma unroll
    for (int k = 0; k < 64; ++k) w[k] = Ws[k * 64 + c];

    int rbase = gb * 32 + (t >> 6) * 8;
    #pragma unroll 1
    for (int it = 0; it < 8; it += 2) {
        int r0 = rbase + it;
        if (r0 >= N) break;                         // wave-uniform
        int r0u = __builtin_amdgcn_readfirstlane(r0);
        int has1 = (r0u + 1 < N);
        const float* __restrict__ h0 = Hx + (size_t)r0u * HID;
        const float* __restrict__ h1 = Hx + (size_t)(has1 ? r0u + 1 : r0u) * HID;
        float a0 = 0.f, a1 = 0.f, a2 = 0.f, a3 = 0.f;
        float b0 = 0.f, b1 = 0.f, b2 = 0.f, b3 = 0.f;
        #pragma unroll
        for (int k = 0; k < 64; k += 4) {
            a0 = fmaf(h0[k],     w[k],     a0);
            b0 = fmaf(h1[k],     w[k],     b0);
            a1 = fmaf(h0[k + 1], w[k + 1], a1);
            b1 = fmaf(h1[k + 1], w[k + 1], b1);
            a2 = fmaf(h0[k + 2], w[k + 2], a2);
            b2 = fmaf(h1[k + 2], w[k + 2], b2);
            a3 = fmaf(h0[k + 3], w[k + 3], a3);
            b3 = fmaf(h1[k + 3], w[k + 3], b3);
        }
        O[(size_t)r0u * HID + c] = (a0 + a1) + (a2 + a3);
        if (has1)
            O[(size_t)(r0u + 1) * HID + c] = (b0 + b1) + (b2 + b3);
    }
}

// ============ pass 2: fill padded CSR per bucket + emit cnt & dinv ============
__global__ __launch_bounds__(512) void k_fill(const int* __restrict__ gcur,
                                              const unsigned int* __restrict__ ebuf,
                                              unsigned short* __restrict__ adj,
                                              int* __restrict__ cnt,
                                              float* __restrict__ dinv, int N) {
    int b = blockIdx.x;
    __shared__ int lcnt[BW];
    int t = threadIdx.x;
    if (t < BW) lcnt[t] = 0;
    __syncthreads();
    int m = min(gcur[b], CAP);
    const unsigned int* eb = ebuf + (size_t)b * CAP;
    for (int i = t; i < m; i += 512) {
        unsigned u = eb[i];
        int cl = u >> 16;
        int r  = u & 0xFFFF;
        int p = atomicAdd(&lcnt[cl], 1);           // LDS atomic
        if (p < PAD) adj[((size_t)(b * BW + cl)) * PAD + p] = (unsigned short)r;
    }
    __syncthreads();
    int node = b * BW + t;
    if (t < BW && node < N) {
        int n = lcnt[t];
        cnt[node] = n;
        dinv[node] = rsqrtf((float)n + 1.0f);
    }
}

// ============ GEMM [N,64]@[64,64] with dinv-fold epilogue (layers 2,3) ============
__global__ __launch_bounds__(256) void k_gemm64(const float* __restrict__ H,
                                                const float* __restrict__ W,
                                                const float* __restrict__ dinv,
                                                float* __restrict__ O, int N) {
    __shared__ float Ws[64 * 64];
    int tid = threadIdx.x;
    #pragma unroll
    for (int i = tid; i < 64 * 64; i += 256) Ws[i] = W[i];
    __syncthreads();
    int c = tid & 63;
    float w[64];
    #pragma unroll
    for (int k = 0; k < 64; ++k) w[k] = Ws[k * 64 + c];

    int rbase = blockIdx.x * 32 + (tid >> 6) * 8;
    #pragma unroll 1
    for (int it = 0; it < 8; it += 2) {
        int r0 = rbase + it;
        if (r0 >= N) break;
        int r0u = __builtin_amdgcn_readfirstlane(r0);
        int has1 = (r0u + 1 < N);
        const float* __restrict__ h0 = H + (size_t)r0u * HID;
        const float* __restrict__ h1 = H + (size_t)(has1 ? r0u + 1 : r0u) * HID;
        float a0 = 0.f, a1 = 0.f, a2 = 0.f, a3 = 0.f;
        float b0 = 0.f, b1 = 0.f, b2 = 0.f, b3 = 0.f;
        #pragma unroll
        for (int k = 0; k < 64; k += 4) {
            a0 = fmaf(h0[k],     w[k],     a0);
            b0 = fmaf(h1[k],     w[k],     b0);
            a1 = fmaf(h0[k + 1], w[k + 1], a1);
            b1 = fmaf(h1[k + 1], w[k + 1], b1);
            a2 = fmaf(h0[k + 2], w[k + 2], a2);
            b2 = fmaf(h1[k + 2], w[k + 2], b2);
            a3 = fmaf(h0[k + 3], w[k + 3], a3);
            b3 = fmaf(h1[k + 3], w[k + 3], b3);
        }
        O[(size_t)r0u * HID + c] = ((a0 + a1) + (a2 + a3)) * dinv[r0u];
        if (has1)
            O[(size_t)(r0u + 1) * HID + c] = ((b0 + b1) + (b2 + b3)) * dinv[r0u + 1];
    }
}

// ============ gather-aggregate: one wave per node, quad layout ============
// edge_scale=1 (layer 1): acc = sum dinv[r]*xw_r + dinv[c]*xw_c   (xw pure)
// edge_scale=0 (layers 2,3): acc = sum xws_r + xws_c              (dinv folded)
// out = acc * dinv[c] + b  (+relu)
__global__ __launch_bounds__(256) void k_gather(const unsigned short* __restrict__ adj,
                                                const int* __restrict__ cnt,
                                                const float* __restrict__ dinv,
                                                const float* __restrict__ xws,
                                                const float* __restrict__ b,
                                                float* __restrict__ out,
                                                int N, int do_relu, int edge_scale) {
    int node = blockIdx.x * 4 + (threadIdx.x >> 6);
    if (node >= N) return;                      // wave-uniform
    int lane = threadIdx.x & 63;
    int q = lane >> 4, j = lane & 15;
    size_t s = (size_t)node * PAD;
    int n = cnt[node];
    float dv = dinv[node];

    float ax = 0.f, ay = 0.f, az = 0.f, aw = 0.f;
    if (edge_scale) {
        for (int i = q; i < n; i += 4) {
            int r = adj[s + i];
            float sc = dinv[r];
            const float4 v = *reinterpret_cast<const float4*>(xws + (size_t)r * HID + j * 4);
            ax = fmaf(v.x, sc, ax); ay = fmaf(v.y, sc, ay);
            az = fmaf(v.z, sc, az); aw = fmaf(v.w, sc, aw);
        }
        if (q == 0) {   // self loop, scaled by dinv[node]
            const float4 sv = *reinterpret_cast<const float4*>(xws + (size_t)node * HID + j * 4);
            ax = fmaf(sv.x, dv, ax); ay = fmaf(sv.y, dv, ay);
            az = fmaf(sv.z, dv, az); aw = fmaf(sv.w, dv, aw);
        }
    } else {
        for (int i = q; i < n; i += 4) {
            int r = adj[s + i];
            const float4 v = *reinterpret_cast<const float4*>(xws + (size_t)r * HID + j * 4);
            ax += v.x; ay += v.y; az += v.z; aw += v.w;
        }
        if (q == 0) {   // self loop
            const float4 sv = *reinterpret_cast<const float4*>(xws + (size_t)node * HID + j * 4);
            ax += sv.x; ay += sv.y; az += sv.z; aw += sv.w;
        }
    }
    ax += __shfl_xor(ax, 16, 64); ay += __shfl_xor(ay, 16, 64);
    az += __shfl_xor(az, 16, 64); aw += __shfl_xor(aw, 16, 64);
    ax += __shfl_xor(ax, 32, 64); ay += __shfl_xor(ay, 32, 64);
    az += __shfl_xor(az, 32, 64); aw += __shfl_xor(aw, 32, 64);

    if (q == 0) {
        const float4 bv = *reinterpret_cast<const float4*>(b + j * 4);
        float4 o;
        o.x = ax * dv + bv.x; o.y = ay * dv + bv.y;
        o.z = az * dv + bv.z; o.w = aw * dv + bv.w;
        if (do_relu) {
            o.x = fmaxf(o.x, 0.f); o.y = fmaxf(o.y, 0.f);
            o.z = fmaxf(o.z, 0.f); o.w = fmaxf(o.w, 0.f);
        }
        *reinterpret_cast<float4*>(out + (size_t)node * HID + j * 4) = o;
    }
}

// ============ fused bstart-scan + mean pool + head: one block per graph ============
__global__ __launch_bounds__(256) void k_pmean(const float* __restrict__ h,
                                               const int* __restrict__ bcnt,
                                               const float* __restrict__ Wl,
                                               const float* __restrict__ bl,
                                               float* __restrict__ out) {
    int g = blockIdx.x;
    int t = threadIdx.x;
    __shared__ int ssum[256];
    int part = 0;
    for (int j = t; j < g; j += 256) part += bcnt[j];
    ssum[t] = part;
    __syncthreads();
    for (int s2 = 128; s2 > 0; s2 >>= 1) {
        if (t < s2) ssum[t] += ssum[t + s2];
        __syncthreads();
    }
    int s = ssum[0];
    int n = bcnt[g];
    int f = t & 63, w = t >> 6;
    float acc = 0.0f;
    for (int i = s + w; i < s + n; i += 4) acc += h[(size_t)i * HID + f];
    __shared__ float lds[256];
    __shared__ float mean[64];
    lds[t] = acc;
    __syncthreads();
    if (w == 0) {
        float tot = lds[f] + lds[64 + f] + lds[128 + f] + lds[192 + f];
        mean[f] = tot / fmaxf((float)n, 1.0f);
    }
    __syncthreads();
    if (t < N_CLS) {
        int c = t;
        float a = bl[c];
        #pragma unroll
        for (int k = 0; k < HID; ++k) a = fmaf(mean[k], Wl[k * N_CLS + c], a);
        out[(size_t)g * N_CLS + c] = a;
    }
}

extern "C" void kernel_launch(void* const* d_in, const int* in_sizes, int n_in,
                              void* d_out, int out_size, void* d_ws, size_t ws_size,
                              hipStream_t stream) {
    const float* x     = (const float*)d_in[0];
    const int*   ei    = (const int*)d_in[1];
    const int*   batch = (const int*)d_in[2];
    const float* W1    = (const float*)d_in[3];
    const float* b1    = (const float*)d_in[4];
    const float* W2    = (const float*)d_in[5];
    const float* b2    = (const float*)d_in[6];
    const float* W3    = (const float*)d_in[7];
    const float* b3    = (const float*)d_in[8];
    const float* Wl    = (const float*)d_in[9];
    const float* bl    = (const float*)d_in[10];
    float* out = (float*)d_out;

    const int N = in_sizes[0] / HID;   // 50000
    const int E = in_sizes[1] / 2;     // 800000
    const int* row = ei;
    const int* col = ei + E;

    // ---- workspace layout (4-byte units); gcur|bcnt contiguous for one memset ----
    char* wsb = (char*)d_ws;
    int*   gcur = (int*)wsb;                               // 392 (NB padded)
    int*   bcnt = gcur + 392;                              // 512
    int*   cnt  = bcnt + 512;                              // 50048
    float* dinv = (float*)(cnt + 50048);                   // 50048
    unsigned int* ebuf = (unsigned int*)(dinv + 50048);    // NB*CAP u32 = 6.4 MB
    unsigned short* adj = (unsigned short*)(ebuf + (size_t)NB * CAP);  // 50048*64 u16
    float* bufA = (float*)(adj + (size_t)50048 * PAD);     // N*64
    float* bufB = bufA + (size_t)N * HID;                  // N*64

    const int T = 256;
    const int nblk  = (N + 255) / 256;                  // 196
    const int nEb   = (E + CHUNK - 1) / CHUNK;          // 391
    const int gGemm = (N + 31) / 32;                    // 1563
    const int gGath = (N + 3) / 4;                      // 12500

    // zero: gcur + bcnt only
    hipMemsetAsync(gcur, 0, (size_t)(392 + 512) * sizeof(int), stream);

    // ---- fused: bin + bhist + pure gemm1 (bin latency hidden under gemm VALU) ----
    k_bin_gemm<<<nEb + nblk + gGemm, T, 0, stream>>>(row, col, E, gcur, ebuf,
                                                     batch, N, bcnt, x, W1, bufA);
    k_fill<<<NB, 512, 0, stream>>>(gcur, ebuf, adj, cnt, dinv, N);

    // ---- layer 1 aggregate (edge_scale applies dinv to pure xw) ----
    k_gather<<<gGath, T, 0, stream>>>(adj, cnt, dinv, bufA, b1, bufB, N, 1, 1);
    // ---- layer 2 ----
    k_gemm64<<<gGemm, T, 0, stream>>>(bufB, W2, dinv, bufA, N);
    k_gather<<<gGath, T, 0, stream>>>(adj, cnt, dinv, bufA, b2, bufB, N, 1, 0);
    // ---- layer 3 ----
    k_gemm64<<<gGemm, T, 0, stream>>>(bufB, W3, dinv, bufA, N);
    k_gather<<<gGath, T, 0, stream>>>(adj, cnt, dinv, bufA, b3, bufB, N, 0, 0);

    // ---- fused scan + pool + head ----
    k_pmean<<<N_GRAPHS, T, 0, stream>>>(bufB, bcnt, Wl, bl, out);
}